// Round 1
// baseline (1864.712 us; speedup 1.0000x reference)
//
#include <hip/hip_runtime.h>

#define T_DIM 4096
#define K1    4096      // H (hidden)
#define I_DIM 11008
#define QMAXF 127.0f

typedef int v4i __attribute__((ext_vector_type(4)));

// ---------------- helpers ----------------

__device__ __forceinline__ void gload16(const void* g, void* l) {
  __builtin_amdgcn_global_load_lds((__attribute__((address_space(1))) unsigned int*)(g),
                                   (__attribute__((address_space(3))) unsigned int*)(l),
                                   16, 0, 0);
}

__device__ __forceinline__ int packq(float a, float b, float c, float d) {
  return ((int)a & 255) | (((int)b & 255) << 8) | (((int)c & 255) << 16) | (((int)d & 255) << 24);
}

// ---------------- pass 1: absmax(x) ----------------

__global__ void absmax_x_kernel(const float4* __restrict__ x4, unsigned* __restrict__ maxbits, int n4) {
  int tid = blockIdx.x * blockDim.x + threadIdx.x;
  int stride = gridDim.x * blockDim.x;
  float m = 0.f;
  for (int i = tid; i < n4; i += stride) {
    float4 v = x4[i];
    m = fmaxf(m, fmaxf(fmaxf(fabsf(v.x), fabsf(v.y)), fmaxf(fabsf(v.z), fabsf(v.w))));
  }
  #pragma unroll
  for (int off = 32; off; off >>= 1) m = fmaxf(m, __shfl_xor(m, off));
  if ((threadIdx.x & 63) == 0) atomicMax(maxbits, __float_as_uint(m));
}

// ---------------- pass 2: quantize x ----------------

__global__ void quant_x_kernel(const float4* __restrict__ x4, v4i* __restrict__ q4,
                               const unsigned* __restrict__ scal) {
  const float sx = __uint_as_float(scal[0]) * (1.0f / QMAXF);
  const long i = (long)blockIdx.x * blockDim.x + threadIdx.x;  // 16 floats per thread
  v4i o;
  #pragma unroll
  for (int j = 0; j < 4; ++j) {
    float4 v = x4[i * 4 + j];
    float a = fminf(fmaxf(rintf(v.x / sx), -QMAXF), QMAXF);
    float b = fminf(fmaxf(rintf(v.y / sx), -QMAXF), QMAXF);
    float c = fminf(fmaxf(rintf(v.z / sx), -QMAXF), QMAXF);
    float d = fminf(fmaxf(rintf(v.w / sx), -QMAXF), QMAXF);
    o[j] = packq(a, b, c, d);
  }
  q4[i] = o;
}

// ---------------- weight f32(int-valued) -> int8 ----------------

__global__ void conv_w_kernel(const float4* __restrict__ w4, v4i* __restrict__ q4) {
  const long i = (long)blockIdx.x * blockDim.x + threadIdx.x;  // 16 floats per thread
  v4i o;
  #pragma unroll
  for (int j = 0; j < 4; ++j) {
    float4 v = w4[i * 4 + j];
    o[j] = packq(rintf(v.x), rintf(v.y), rintf(v.z), rintf(v.w));
  }
  q4[i] = o;
}

// ---------------- GEMM1 fused: gate/up int8 GEMM + dequant + silu*mul + h absmax ----------------
// C[t,j] = sum_k qx[t,k]*W[j,k], W row-major [2I][K1]. Block: 64 rows x (128 gate + 128 up cols).
// LDS tiles slot-major: tile[slot][row][16B], slot = k16 group, so ds_read_b128 frags are conflict-free.

__global__ __launch_bounds__(256, 2)
void gemm1_silu_kernel(const signed char* __restrict__ qx,
                       const signed char* __restrict__ w8,
                       const float* __restrict__ sgu,
                       unsigned* __restrict__ scal,
                       float* __restrict__ hbuf)
{
  __shared__ signed char As[4 * 64 * 16];    // 4 KB
  __shared__ signed char Bg[4 * 128 * 16];   // 8 KB
  __shared__ signed char Bu[4 * 128 * 16];   // 8 KB

  const int tid  = threadIdx.x;
  const int lane = tid & 63;
  const int wid  = tid >> 6;
  const int wr   = wid >> 1, wc = wid & 1;
  const int ln15 = lane & 15;
  const int klg  = lane >> 4;

  const int brow = blockIdx.y * 64;
  const int bcol = blockIdx.x * 128;

  // staging: A one 16B inst/thread (slot=tid>>6,row=tid&63); B two insts/thread
  const signed char* ga = qx + (size_t)(brow + (tid & 63)) * K1 + (tid >> 6) * 16;
  const int o0 = tid * 16, o1 = 4096 + tid * 16;
  const int s0 = o0 >> 11, r0 = (o0 >> 4) & 127;
  const int s1 = o1 >> 11, r1 = (o1 >> 4) & 127;
  const signed char* gbg0 = w8 + (size_t)(bcol + r0) * K1 + s0 * 16;
  const signed char* gbg1 = w8 + (size_t)(bcol + r1) * K1 + s1 * 16;
  const signed char* gbu0 = w8 + (size_t)(I_DIM + bcol + r0) * K1 + s0 * 16;
  const signed char* gbu1 = w8 + (size_t)(I_DIM + bcol + r1) * K1 + s1 * 16;
  signed char* lA   = &As[tid * 16];
  signed char* lBg0 = &Bg[o0];
  signed char* lBg1 = &Bg[o1];
  signed char* lBu0 = &Bu[o0];
  signed char* lBu1 = &Bu[o1];

  // fragment LDS offsets (slot-major)
  int aoff[2], boff[4];
  #pragma unroll
  for (int rb = 0; rb < 2; ++rb) aoff[rb] = klg * 1024 + (wr * 32 + rb * 16 + ln15) * 16;
  #pragma unroll
  for (int cb = 0; cb < 4; ++cb) boff[cb] = klg * 2048 + (wc * 64 + cb * 16 + ln15) * 16;

  v4i zero = {0, 0, 0, 0};
  v4i accg[2][4], accu[2][4];
  #pragma unroll
  for (int rb = 0; rb < 2; ++rb)
    #pragma unroll
    for (int cb = 0; cb < 4; ++cb) { accg[rb][cb] = zero; accu[rb][cb] = zero; }

  auto stage = [&](int kt) {
    const int ko = kt * 64;
    gload16(ga + ko, lA);
    gload16(gbg0 + ko, lBg0);
    gload16(gbg1 + ko, lBg1);
    gload16(gbu0 + ko, lBu0);
    gload16(gbu1 + ko, lBu1);
  };

  stage(0);
  const int nk = K1 / 64;
  for (int kt = 0; kt < nk; ++kt) {
    __syncthreads();                 // staged tile kt visible
    v4i af[2], bgf[4], buf_[4];
    #pragma unroll
    for (int rb = 0; rb < 2; ++rb) af[rb] = *(const v4i*)&As[aoff[rb]];
    #pragma unroll
    for (int cb = 0; cb < 4; ++cb) {
      bgf[cb]  = *(const v4i*)&Bg[boff[cb]];
      buf_[cb] = *(const v4i*)&Bu[boff[cb]];
    }
    __syncthreads();                 // frag reads done before overwrite
    if (kt + 1 < nk) stage(kt + 1);  // prefetch overlaps MFMA
    #pragma unroll
    for (int rb = 0; rb < 2; ++rb)
      #pragma unroll
      for (int cb = 0; cb < 4; ++cb) {
        accg[rb][cb] = __builtin_amdgcn_mfma_i32_16x16x64_i8(af[rb], bgf[cb],  accg[rb][cb], 0, 0, 0);
        accu[rb][cb] = __builtin_amdgcn_mfma_i32_16x16x64_i8(af[rb], buf_[cb], accu[rb][cb], 0, 0, 0);
      }
  }

  // epilogue: dequant + silu*mul, write h, track block max|h|
  const float xsc = __uint_as_float(scal[0]) * (1.0f / QMAXF);
  float hmax = 0.f;
  #pragma unroll
  for (int rb = 0; rb < 2; ++rb) {
    const int row0 = brow + wr * 32 + rb * 16 + (lane >> 4) * 4;
    #pragma unroll
    for (int cb = 0; cb < 4; ++cb) {
      const int col = bcol + wc * 64 + cb * 16 + ln15;
      const float sg = sgu[col] * xsc;
      const float su = sgu[I_DIM + col] * xsc;
      #pragma unroll
      for (int q = 0; q < 4; ++q) {
        float g = (float)accg[rb][cb][q] * sg;
        float u = (float)accu[rb][cb][q] * su;
        float hv = (g / (1.f + expf(-g))) * u;
        hmax = fmaxf(hmax, fabsf(hv));
        hbuf[(size_t)(row0 + q) * I_DIM + col] = hv;
      }
    }
  }
  #pragma unroll
  for (int off = 32; off; off >>= 1) hmax = fmaxf(hmax, __shfl_xor(hmax, off));
  if (lane == 0) atomicMax(scal + 1, __float_as_uint(hmax));
}

// ---------------- quantize h ----------------

__global__ void quant_h_kernel(const float4* __restrict__ h4, v4i* __restrict__ q4,
                               const unsigned* __restrict__ scal) {
  const float hs = __uint_as_float(scal[1]) * (1.0f / QMAXF);
  const long i = (long)blockIdx.x * blockDim.x + threadIdx.x;
  v4i o;
  #pragma unroll
  for (int j = 0; j < 4; ++j) {
    float4 v = h4[i * 4 + j];
    float a = fminf(fmaxf(rintf(v.x / hs), -QMAXF), QMAXF);
    float b = fminf(fmaxf(rintf(v.y / hs), -QMAXF), QMAXF);
    float c = fminf(fmaxf(rintf(v.z / hs), -QMAXF), QMAXF);
    float d = fminf(fmaxf(rintf(v.w / hs), -QMAXF), QMAXF);
    o[j] = packq(a, b, c, d);
  }
  q4[i] = o;
}

__global__ void hscale_out_kernel(const unsigned* __restrict__ scal, float* __restrict__ dst) {
  dst[0] = __uint_as_float(scal[1]) * (1.0f / QMAXF);
}

// ---------------- GEMM2: out = (qh @ wdn^T) * (h_scale * s_down) ----------------

__global__ __launch_bounds__(256, 2)
void gemm2_kernel(const signed char* __restrict__ qh,
                  const signed char* __restrict__ w8,
                  const float* __restrict__ sdn,
                  const unsigned* __restrict__ scal,
                  float* __restrict__ out)
{
  __shared__ signed char As[4 * 128 * 16];   // 8 KB
  __shared__ signed char Bs[4 * 128 * 16];   // 8 KB

  const int tid  = threadIdx.x;
  const int lane = tid & 63;
  const int wid  = tid >> 6;
  const int wr   = wid >> 1, wc = wid & 1;
  const int ln15 = lane & 15;
  const int klg  = lane >> 4;

  const int brow = blockIdx.y * 128;
  const int bcol = blockIdx.x * 128;

  const int o0 = tid * 16, o1 = 4096 + tid * 16;
  const int s0 = o0 >> 11, r0 = (o0 >> 4) & 127;
  const int s1 = o1 >> 11, r1 = (o1 >> 4) & 127;
  const signed char* ga0 = qh + (size_t)(brow + r0) * I_DIM + s0 * 16;
  const signed char* ga1 = qh + (size_t)(brow + r1) * I_DIM + s1 * 16;
  const signed char* gb0 = w8 + (size_t)(bcol + r0) * I_DIM + s0 * 16;
  const signed char* gb1 = w8 + (size_t)(bcol + r1) * I_DIM + s1 * 16;
  signed char* lA0 = &As[o0];
  signed char* lA1 = &As[o1];
  signed char* lB0 = &Bs[o0];
  signed char* lB1 = &Bs[o1];

  int aoff[4], boff[4];
  #pragma unroll
  for (int rb = 0; rb < 4; ++rb) aoff[rb] = klg * 2048 + (wr * 64 + rb * 16 + ln15) * 16;
  #pragma unroll
  for (int cb = 0; cb < 4; ++cb) boff[cb] = klg * 2048 + (wc * 64 + cb * 16 + ln15) * 16;

  v4i zero = {0, 0, 0, 0};
  v4i acc[4][4];
  #pragma unroll
  for (int rb = 0; rb < 4; ++rb)
    #pragma unroll
    for (int cb = 0; cb < 4; ++cb) acc[rb][cb] = zero;

  auto stage = [&](int kt) {
    const int ko = kt * 64;
    gload16(ga0 + ko, lA0);
    gload16(ga1 + ko, lA1);
    gload16(gb0 + ko, lB0);
    gload16(gb1 + ko, lB1);
  };

  stage(0);
  const int nk = I_DIM / 64;  // 172
  for (int kt = 0; kt < nk; ++kt) {
    __syncthreads();
    v4i af[4], bf[4];
    #pragma unroll
    for (int rb = 0; rb < 4; ++rb) af[rb] = *(const v4i*)&As[aoff[rb]];
    #pragma unroll
    for (int cb = 0; cb < 4; ++cb) bf[cb] = *(const v4i*)&Bs[boff[cb]];
    __syncthreads();
    if (kt + 1 < nk) stage(kt + 1);
    #pragma unroll
    for (int rb = 0; rb < 4; ++rb)
      #pragma unroll
      for (int cb = 0; cb < 4; ++cb)
        acc[rb][cb] = __builtin_amdgcn_mfma_i32_16x16x64_i8(af[rb], bf[cb], acc[rb][cb], 0, 0, 0);
  }

  const float hsc = __uint_as_float(scal[1]) * (1.0f / QMAXF);
  #pragma unroll
  for (int rb = 0; rb < 4; ++rb) {
    const int row0 = brow + wr * 64 + rb * 16 + (lane >> 4) * 4;
    #pragma unroll
    for (int cb = 0; cb < 4; ++cb) {
      const int col = bcol + wc * 64 + cb * 16 + ln15;
      const float s = sdn[col] * hsc;
      #pragma unroll
      for (int q = 0; q < 4; ++q)
        out[(size_t)(row0 + q) * K1 + col] = (float)acc[rb][cb][q] * s;
    }
  }
}

// ---------------- launch ----------------

extern "C" void kernel_launch(void* const* d_in, const int* in_sizes, int n_in,
                              void* d_out, int out_size, void* d_ws, size_t ws_size,
                              hipStream_t stream) {
  (void)in_sizes; (void)n_in; (void)out_size; (void)ws_size;
  const float* x   = (const float*)d_in[0];
  const float* wgu = (const float*)d_in[1];
  const float* sgu = (const float*)d_in[2];
  const float* wdn = (const float*)d_in[3];
  const float* sdn = (const float*)d_in[4];
  float* out = (float*)d_out;
  char* ws = (char*)d_ws;

  // ws layout (16B aligned): total ~360 MB
  signed char* qx  = (signed char*)(ws + 0LL);           // 16,777,216
  signed char* w8g = (signed char*)(ws + 16777216LL);    // 90,177,536
  signed char* w8d = (signed char*)(ws + 106954752LL);   // 45,088,768
  signed char* qh  = (signed char*)(ws + 152043520LL);   // 45,088,768
  float*       hb  = (float*)      (ws + 197132288LL);   // 180,355,072
  unsigned*    scal= (unsigned*)   (ws + 377487360LL);   // 256

  hipMemsetAsync(scal, 0, 256, stream);
  absmax_x_kernel<<<2048, 256, 0, stream>>>((const float4*)x, scal, T_DIM * K1 / 4);
  quant_x_kernel<<<4096, 256, 0, stream>>>((const float4*)x, (v4i*)qx, scal);
  conv_w_kernel<<<22016, 256, 0, stream>>>((const float4*)wgu, (v4i*)w8g);
  conv_w_kernel<<<11008, 256, 0, stream>>>((const float4*)wdn, (v4i*)w8d);

  dim3 g1(I_DIM / 128, T_DIM / 64);   // (86, 64)
  gemm1_silu_kernel<<<g1, 256, 0, stream>>>(qx, w8g, sgu, scal, hb);

  quant_h_kernel<<<11008, 256, 0, stream>>>((const float4*)hb, (v4i*)qh, scal);
  hscale_out_kernel<<<1, 1, 0, stream>>>(scal, out + (size_t)T_DIM * K1);

  dim3 g2(K1 / 128, T_DIM / 128);     // (32, 32)
  gemm2_kernel<<<g2, 256, 0, stream>>>(qh, w8d, sdn, scal, out);
}

// Round 2
// 1536.674 us; speedup vs baseline: 1.2135x; 1.2135x over previous
//
#include <hip/hip_runtime.h>

#define T_DIM 4096
#define K1    4096      // H (hidden)
#define I_DIM 11008
#define QMAXF 127.0f

typedef int v4i __attribute__((ext_vector_type(4)));

// ---------------- helpers ----------------

__device__ __forceinline__ void gload16(const void* g, void* l) {
  __builtin_amdgcn_global_load_lds((__attribute__((address_space(1))) unsigned int*)(g),
                                   (__attribute__((address_space(3))) unsigned int*)(l),
                                   16, 0, 0);
}

__device__ __forceinline__ int packq(float a, float b, float c, float d) {
  return ((int)a & 255) | (((int)b & 255) << 8) | (((int)c & 255) << 16) | (((int)d & 255) << 24);
}

// ---------------- pass 1: absmax(x) ----------------

__global__ void absmax_x_kernel(const float4* __restrict__ x4, unsigned* __restrict__ maxbits, int n4) {
  int tid = blockIdx.x * blockDim.x + threadIdx.x;
  int stride = gridDim.x * blockDim.x;
  float m = 0.f;
  for (int i = tid; i < n4; i += stride) {
    float4 v = x4[i];
    m = fmaxf(m, fmaxf(fmaxf(fabsf(v.x), fabsf(v.y)), fmaxf(fabsf(v.z), fabsf(v.w))));
  }
  #pragma unroll
  for (int off = 32; off; off >>= 1) m = fmaxf(m, __shfl_xor(m, off));
  if ((threadIdx.x & 63) == 0) atomicMax(maxbits, __float_as_uint(m));
}

// ---------------- pass 2: quantize x ----------------

__global__ void quant_x_kernel(const float4* __restrict__ x4, v4i* __restrict__ q4,
                               const unsigned* __restrict__ scal) {
  const float sx = __uint_as_float(scal[0]) * (1.0f / QMAXF);
  const long i = (long)blockIdx.x * blockDim.x + threadIdx.x;  // 16 floats per thread
  v4i o;
  #pragma unroll
  for (int j = 0; j < 4; ++j) {
    float4 v = x4[i * 4 + j];
    float a = fminf(fmaxf(rintf(v.x / sx), -QMAXF), QMAXF);
    float b = fminf(fmaxf(rintf(v.y / sx), -QMAXF), QMAXF);
    float c = fminf(fmaxf(rintf(v.z / sx), -QMAXF), QMAXF);
    float d = fminf(fmaxf(rintf(v.w / sx), -QMAXF), QMAXF);
    o[j] = packq(a, b, c, d);
  }
  q4[i] = o;
}

// ---------------- weight f32(int-valued) -> int8 ----------------

__global__ void conv_w_kernel(const float4* __restrict__ w4, v4i* __restrict__ q4) {
  const long i = (long)blockIdx.x * blockDim.x + threadIdx.x;  // 16 floats per thread
  v4i o;
  #pragma unroll
  for (int j = 0; j < 4; ++j) {
    float4 v = w4[i * 4 + j];
    o[j] = packq(rintf(v.x), rintf(v.y), rintf(v.z), rintf(v.w));
  }
  q4[i] = o;
}

// ---------------- GEMM1 fused: int8 GEMM + dequant + silu*mul + h absmax ----------------
// Tile: 128 rows x (128 gate + 128 up). 512 threads, 8 waves (2 row x 4 colpair).
// 3-deep LDS pipeline, prefetch distance 2, counted vmcnt (never 0 in steady state).
// LDS slot-major [slot][row][16B] so global_load_lds dest is linear and ds_read_b128 conflict-free.

__global__ __launch_bounds__(512, 4)
void gemm1_silu_kernel(const signed char* __restrict__ qx,
                       const signed char* __restrict__ w8,
                       const float* __restrict__ sgu,
                       unsigned* __restrict__ scal,
                       float* __restrict__ hbuf)
{
  __shared__ signed char As[3][8192];
  __shared__ signed char Bg[3][8192];
  __shared__ signed char Bu[3][8192];

  const int tid  = threadIdx.x;
  const int lane = tid & 63;
  const int wid  = tid >> 6;       // 0..7
  const int wr   = wid >> 2;       // 0..1
  const int wc   = wid & 3;        // 0..3
  const int ln15 = lane & 15;
  const int klg  = lane >> 4;

  // XCD-chunked bijective swizzle; within a chunk rows vary fastest -> B panel L2-resident
  const int lin = blockIdx.x;                  // 0..2751 (= 8 * 344)
  const int sw  = (lin & 7) * 344 + (lin >> 3);
  const int brow = (sw & 31) * 128;            // 32 row blocks
  const int bcol = (sw >> 5) * 128;            // 86 col blocks

  // staging: 1 load each of A/Bg/Bu per thread (3 = vmcnt per stage)
  const int srow  = tid & 127;
  const int sslot = tid >> 7;                  // 0..3
  const signed char* gA  = qx + (size_t)(brow + srow) * K1 + sslot * 16;
  const signed char* gBg = w8 + (size_t)(bcol + srow) * K1 + sslot * 16;
  const signed char* gBu = w8 + (size_t)(I_DIM + bcol + srow) * K1 + sslot * 16;
  const int loff = tid * 16;

  // fragment LDS offsets (buffer-relative, slot-major)
  int aoff[4], goff[2];
  #pragma unroll
  for (int rb = 0; rb < 4; ++rb) aoff[rb] = klg * 2048 + (wr * 64 + rb * 16 + ln15) * 16;
  #pragma unroll
  for (int cb = 0; cb < 2; ++cb) goff[cb] = klg * 2048 + (wc * 32 + cb * 16 + ln15) * 16;

  v4i zero = {0, 0, 0, 0};
  v4i accg[4][2], accu[4][2];
  #pragma unroll
  for (int rb = 0; rb < 4; ++rb)
    #pragma unroll
    for (int cb = 0; cb < 2; ++cb) { accg[rb][cb] = zero; accu[rb][cb] = zero; }

  auto stage = [&](int kt, int b) {
    const int ko = kt * 64;
    gload16(gA + ko,  &As[b][loff]);
    gload16(gBg + ko, &Bg[b][loff]);
    gload16(gBu + ko, &Bu[b][loff]);
  };

  stage(0, 0);
  stage(1, 1);
  const int nk = K1 / 64;  // 64
  int cbuf = 0, sbuf = 2;
  for (int kt = 0; kt < nk; ++kt) {
    // tile kt resident: all but the newest in-flight stage complete (in-order vmcnt)
    if (kt < nk - 1) asm volatile("s_waitcnt vmcnt(3)" ::: "memory");
    else             asm volatile("s_waitcnt vmcnt(0)" ::: "memory");
    __builtin_amdgcn_s_barrier();
    asm volatile("" ::: "memory");            // fence: nothing moves above the barrier
    if (kt + 2 < nk) stage(kt + 2, sbuf);     // issue next-next tile; 2 iters of latency budget

    v4i af[4], bgf[2], buf_[2];
    #pragma unroll
    for (int rb = 0; rb < 4; ++rb) af[rb] = *(const v4i*)&As[cbuf][aoff[rb]];
    #pragma unroll
    for (int cb = 0; cb < 2; ++cb) {
      bgf[cb]  = *(const v4i*)&Bg[cbuf][goff[cb]];
      buf_[cb] = *(const v4i*)&Bu[cbuf][goff[cb]];
    }
    #pragma unroll
    for (int rb = 0; rb < 4; ++rb)
      #pragma unroll
      for (int cb = 0; cb < 2; ++cb) {
        accg[rb][cb] = __builtin_amdgcn_mfma_i32_16x16x64_i8(af[rb], bgf[cb],  accg[rb][cb], 0, 0, 0);
        accu[rb][cb] = __builtin_amdgcn_mfma_i32_16x16x64_i8(af[rb], buf_[cb], accu[rb][cb], 0, 0, 0);
      }
    cbuf = (cbuf + 1 == 3) ? 0 : cbuf + 1;
    sbuf = (sbuf + 1 == 3) ? 0 : sbuf + 1;
  }

  // epilogue: dequant + silu*mul, write h, track max|h|
  const float xsc = __uint_as_float(scal[0]) * (1.0f / QMAXF);
  float hmax = 0.f;
  #pragma unroll
  for (int rb = 0; rb < 4; ++rb) {
    const int row0 = brow + wr * 64 + rb * 16 + klg * 4;
    #pragma unroll
    for (int cb = 0; cb < 2; ++cb) {
      const int col = bcol + wc * 32 + cb * 16 + ln15;
      const float sg = sgu[col] * xsc;
      const float su = sgu[I_DIM + col] * xsc;
      #pragma unroll
      for (int q = 0; q < 4; ++q) {
        float g = (float)accg[rb][cb][q] * sg;
        float u = (float)accu[rb][cb][q] * su;
        float hv = (g / (1.f + expf(-g))) * u;
        hmax = fmaxf(hmax, fabsf(hv));
        hbuf[(size_t)(row0 + q) * I_DIM + col] = hv;
      }
    }
  }
  #pragma unroll
  for (int off = 32; off; off >>= 1) hmax = fmaxf(hmax, __shfl_xor(hmax, off));
  if (lane == 0) atomicMax(scal + 1, __float_as_uint(hmax));
}

// ---------------- quantize h ----------------

__global__ void quant_h_kernel(const float4* __restrict__ h4, v4i* __restrict__ q4,
                               const unsigned* __restrict__ scal) {
  const float hs = __uint_as_float(scal[1]) * (1.0f / QMAXF);
  const long i = (long)blockIdx.x * blockDim.x + threadIdx.x;
  v4i o;
  #pragma unroll
  for (int j = 0; j < 4; ++j) {
    float4 v = h4[i * 4 + j];
    float a = fminf(fmaxf(rintf(v.x / hs), -QMAXF), QMAXF);
    float b = fminf(fmaxf(rintf(v.y / hs), -QMAXF), QMAXF);
    float c = fminf(fmaxf(rintf(v.z / hs), -QMAXF), QMAXF);
    float d = fminf(fmaxf(rintf(v.w / hs), -QMAXF), QMAXF);
    o[j] = packq(a, b, c, d);
  }
  q4[i] = o;
}

__global__ void hscale_out_kernel(const unsigned* __restrict__ scal, float* __restrict__ dst) {
  dst[0] = __uint_as_float(scal[1]) * (1.0f / QMAXF);
}

// ---------------- GEMM2: out = (qh @ wdn^T) * (h_scale * s_down) ----------------
// 128x128 tile, 256 threads, 3-deep pipeline like gemm1.

__global__ __launch_bounds__(256, 3)
void gemm2_kernel(const signed char* __restrict__ qh,
                  const signed char* __restrict__ w8,
                  const float* __restrict__ sdn,
                  const unsigned* __restrict__ scal,
                  float* __restrict__ out)
{
  __shared__ signed char As[3][8192];
  __shared__ signed char Bs[3][8192];

  const int tid  = threadIdx.x;
  const int lane = tid & 63;
  const int wid  = tid >> 6;
  const int wr   = wid >> 1, wc = wid & 1;
  const int ln15 = lane & 15;
  const int klg  = lane >> 4;

  const int lin = blockIdx.x;                  // 0..1023 (= 8 * 128)
  const int sw  = (lin & 7) * 128 + (lin >> 3);
  const int brow = (sw & 31) * 128;
  const int bcol = (sw >> 5) * 128;

  const int o0 = tid * 16, o1 = 4096 + tid * 16;
  const int s0 = o0 >> 11, r0 = (o0 >> 4) & 127;
  const int s1 = o1 >> 11, r1 = (o1 >> 4) & 127;
  const signed char* ga0 = qh + (size_t)(brow + r0) * I_DIM + s0 * 16;
  const signed char* ga1 = qh + (size_t)(brow + r1) * I_DIM + s1 * 16;
  const signed char* gb0 = w8 + (size_t)(bcol + r0) * I_DIM + s0 * 16;
  const signed char* gb1 = w8 + (size_t)(bcol + r1) * I_DIM + s1 * 16;

  int aoff[4], boff[4];
  #pragma unroll
  for (int rb = 0; rb < 4; ++rb) aoff[rb] = klg * 2048 + (wr * 64 + rb * 16 + ln15) * 16;
  #pragma unroll
  for (int cb = 0; cb < 4; ++cb) boff[cb] = klg * 2048 + (wc * 64 + cb * 16 + ln15) * 16;

  v4i zero = {0, 0, 0, 0};
  v4i acc[4][4];
  #pragma unroll
  for (int rb = 0; rb < 4; ++rb)
    #pragma unroll
    for (int cb = 0; cb < 4; ++cb) acc[rb][cb] = zero;

  auto stage = [&](int kt, int b) {
    const int ko = kt * 64;
    gload16(ga0 + ko, &As[b][o0]);
    gload16(ga1 + ko, &As[b][o1]);
    gload16(gb0 + ko, &Bs[b][o0]);
    gload16(gb1 + ko, &Bs[b][o1]);
  };

  stage(0, 0);
  stage(1, 1);
  const int nk = I_DIM / 64;  // 172
  int cbuf = 0, sbuf = 2;
  for (int kt = 0; kt < nk; ++kt) {
    if (kt < nk - 1) asm volatile("s_waitcnt vmcnt(4)" ::: "memory");
    else             asm volatile("s_waitcnt vmcnt(0)" ::: "memory");
    __builtin_amdgcn_s_barrier();
    asm volatile("" ::: "memory");
    if (kt + 2 < nk) stage(kt + 2, sbuf);

    v4i af[4], bf[4];
    #pragma unroll
    for (int rb = 0; rb < 4; ++rb) af[rb] = *(const v4i*)&As[cbuf][aoff[rb]];
    #pragma unroll
    for (int cb = 0; cb < 4; ++cb) bf[cb] = *(const v4i*)&Bs[cbuf][boff[cb]];
    #pragma unroll
    for (int rb = 0; rb < 4; ++rb)
      #pragma unroll
      for (int cb = 0; cb < 4; ++cb)
        acc[rb][cb] = __builtin_amdgcn_mfma_i32_16x16x64_i8(af[rb], bf[cb], acc[rb][cb], 0, 0, 0);
    cbuf = (cbuf + 1 == 3) ? 0 : cbuf + 1;
    sbuf = (sbuf + 1 == 3) ? 0 : sbuf + 1;
  }

  const float hsc = __uint_as_float(scal[1]) * (1.0f / QMAXF);
  #pragma unroll
  for (int rb = 0; rb < 4; ++rb) {
    const int row0 = brow + wr * 64 + rb * 16 + klg * 4;
    #pragma unroll
    for (int cb = 0; cb < 4; ++cb) {
      const int col = bcol + wc * 64 + cb * 16 + ln15;
      const float s = sdn[col] * hsc;
      #pragma unroll
      for (int q = 0; q < 4; ++q)
        out[(size_t)(row0 + q) * K1 + col] = (float)acc[rb][cb][q] * s;
    }
  }
}

// ---------------- launch ----------------

extern "C" void kernel_launch(void* const* d_in, const int* in_sizes, int n_in,
                              void* d_out, int out_size, void* d_ws, size_t ws_size,
                              hipStream_t stream) {
  (void)in_sizes; (void)n_in; (void)out_size; (void)ws_size;
  const float* x   = (const float*)d_in[0];
  const float* wgu = (const float*)d_in[1];
  const float* sgu = (const float*)d_in[2];
  const float* wdn = (const float*)d_in[3];
  const float* sdn = (const float*)d_in[4];
  float* out = (float*)d_out;
  char* ws = (char*)d_ws;

  // ws layout (16B aligned): total ~360 MB
  signed char* qx  = (signed char*)(ws + 0LL);           // 16,777,216
  signed char* w8g = (signed char*)(ws + 16777216LL);    // 90,177,536
  signed char* w8d = (signed char*)(ws + 106954752LL);   // 45,088,768
  signed char* qh  = (signed char*)(ws + 152043520LL);   // 45,088,768
  float*       hb  = (float*)      (ws + 197132288LL);   // 180,355,072
  unsigned*    scal= (unsigned*)   (ws + 377487360LL);   // 256

  hipMemsetAsync(scal, 0, 256, stream);
  absmax_x_kernel<<<2048, 256, 0, stream>>>((const float4*)x, scal, T_DIM * K1 / 4);
  quant_x_kernel<<<4096, 256, 0, stream>>>((const float4*)x, (v4i*)qx, scal);
  conv_w_kernel<<<22016, 256, 0, stream>>>((const float4*)wgu, (v4i*)w8g);
  conv_w_kernel<<<11008, 256, 0, stream>>>((const float4*)wdn, (v4i*)w8d);

  gemm1_silu_kernel<<<2752, 512, 0, stream>>>(qx, w8g, sgu, scal, hb);

  quant_h_kernel<<<11008, 256, 0, stream>>>((const float4*)hb, (v4i*)qh, scal);
  hscale_out_kernel<<<1, 1, 0, stream>>>(scal, out + (size_t)T_DIM * K1);

  gemm2_kernel<<<1024, 256, 0, stream>>>(qh, w8d, sdn, scal, out);
}

// Round 3
// 1321.441 us; speedup vs baseline: 1.4111x; 1.1629x over previous
//
#include <hip/hip_runtime.h>

#define T_DIM 4096
#define K1    4096      // H (hidden)
#define I_DIM 11008
#define QMAXF 127.0f

typedef int v4i __attribute__((ext_vector_type(4)));

// ---------------- helpers ----------------

__device__ __forceinline__ void gload16(const void* g, void* l) {
  __builtin_amdgcn_global_load_lds((__attribute__((address_space(1))) unsigned int*)(g),
                                   (__attribute__((address_space(3))) unsigned int*)(l),
                                   16, 0, 0);
}

__device__ __forceinline__ int packq(float a, float b, float c, float d) {
  return ((int)a & 255) | (((int)b & 255) << 8) | (((int)c & 255) << 16) | (((int)d & 255) << 24);
}

// ---------------- pass 1: absmax(x) ----------------

__global__ void absmax_x_kernel(const float4* __restrict__ x4, unsigned* __restrict__ maxbits, int n4) {
  int tid = blockIdx.x * blockDim.x + threadIdx.x;
  int stride = gridDim.x * blockDim.x;
  float m = 0.f;
  for (int i = tid; i < n4; i += stride) {
    float4 v = x4[i];
    m = fmaxf(m, fmaxf(fmaxf(fabsf(v.x), fabsf(v.y)), fmaxf(fabsf(v.z), fabsf(v.w))));
  }
  #pragma unroll
  for (int off = 32; off; off >>= 1) m = fmaxf(m, __shfl_xor(m, off));
  if ((threadIdx.x & 63) == 0) atomicMax(maxbits, __float_as_uint(m));
}

// ---------------- pass 2: quantize x ----------------

__global__ void quant_x_kernel(const float4* __restrict__ x4, v4i* __restrict__ q4,
                               const unsigned* __restrict__ scal) {
  const float sx = __uint_as_float(scal[0]) * (1.0f / QMAXF);
  const long i = (long)blockIdx.x * blockDim.x + threadIdx.x;  // 16 floats per thread
  v4i o;
  #pragma unroll
  for (int j = 0; j < 4; ++j) {
    float4 v = x4[i * 4 + j];
    float a = fminf(fmaxf(rintf(v.x / sx), -QMAXF), QMAXF);
    float b = fminf(fmaxf(rintf(v.y / sx), -QMAXF), QMAXF);
    float c = fminf(fmaxf(rintf(v.z / sx), -QMAXF), QMAXF);
    float d = fminf(fmaxf(rintf(v.w / sx), -QMAXF), QMAXF);
    o[j] = packq(a, b, c, d);
  }
  q4[i] = o;
}

// ---------------- weight f32(int-valued) -> int8 ----------------

__global__ void conv_w_kernel(const float4* __restrict__ w4, v4i* __restrict__ q4) {
  const long i = (long)blockIdx.x * blockDim.x + threadIdx.x;  // 16 floats per thread
  v4i o;
  #pragma unroll
  for (int j = 0; j < 4; ++j) {
    float4 v = w4[i * 4 + j];
    o[j] = packq(rintf(v.x), rintf(v.y), rintf(v.z), rintf(v.w));
  }
  q4[i] = o;
}

// ---------------- GEMM1 fused: int8 GEMM + dequant + silu*mul + h absmax ----------------
// BM=256 rows x 128 out cols (gate 128 B-rows + up 128 B-rows), BK=64.
// 512 threads = 8 waves (2 row-halves x 4 col-groups of 32).
// 3-buffer LDS, distance-2 prefetch, 2 phases/K-tile of 16 MFMA with
// per-phase {ds_read || stage || barrier || lgkm0 || setprio MFMA} interleave.
// LDS layout per buf: [half h][slot k/16][128 rows][16B] -- gload dest linear, ds_read conflict-free.

__global__ __launch_bounds__(512, 2)
void gemm1_silu_kernel(const signed char* __restrict__ qx,
                       const signed char* __restrict__ w8,
                       const float* __restrict__ sgu,
                       unsigned* __restrict__ scal,
                       float* __restrict__ hbuf)
{
  __shared__ signed char As[3][16384];
  __shared__ signed char Bs[3][16384];

  const int tid  = threadIdx.x;
  const int lane = tid & 63;
  const int wid  = tid >> 6;       // 0..7
  const int wr   = wid >> 2;       // 0..1  row half (128 rows)
  const int wc   = wid & 3;        // 0..3  col group (32 cols)
  const int ln15 = lane & 15;
  const int klg  = lane >> 4;

  // XCD-chunked bijective swizzle (1376 = 8*172); rows fastest -> B panel L2-resident
  const int lin = blockIdx.x;
  const int sw  = (lin & 7) * 172 + (lin >> 3);
  const int brow = (sw & 15) * 256;
  const int bcol = (sw >> 4) * 128;

  // staging addresses: 4 gloads/thread per K-tile (A half0/half1, B gate/up)
  const int sr = tid & 127, ss = tid >> 7;
  const signed char* gA0 = qx + (size_t)(brow + sr) * K1 + ss * 16;
  const signed char* gA1 = qx + (size_t)(brow + 128 + sr) * K1 + ss * 16;
  const signed char* gB0 = w8 + (size_t)(bcol + sr) * K1 + ss * 16;
  const signed char* gB1 = w8 + (size_t)(I_DIM + bcol + sr) * K1 + ss * 16;
  const int l0 = tid * 16, l1 = 8192 + tid * 16;

  // fragment bases (immediate-foldable offsets m*256 / n*256)
  const int abase = wr * 8192 + klg * 2048 + ln15 * 16;
  const int gbase = klg * 2048 + (wc * 32 + ln15) * 16;

  v4i zero = {0, 0, 0, 0};
  v4i accg[8][2], accu[8][2];
  #pragma unroll
  for (int m = 0; m < 8; ++m)
    #pragma unroll
    for (int n = 0; n < 2; ++n) { accg[m][n] = zero; accu[m][n] = zero; }

  auto stage01 = [&](int kt, int b) {   // A half0 + B gate half
    gload16(gA0 + kt * 64, &As[b][l0]);
    gload16(gB0 + kt * 64, &Bs[b][l0]);
  };
  auto stage23 = [&](int kt, int b) {   // A half1 + B up half
    gload16(gA1 + kt * 64, &As[b][l1]);
    gload16(gB1 + kt * 64, &Bs[b][l1]);
  };

  stage01(0, 0); stage23(0, 0);
  stage01(1, 1); stage23(1, 1);

  const int nk = K1 / 64;  // 64
  int cb = 0, sb = 2;
  for (int kt = 0; kt < nk; ++kt) {
    // K-tile kt resident (its 4 loads are the oldest; allow kt+1's 4 outstanding)
    if (kt < nk - 1) asm volatile("s_waitcnt vmcnt(4)" ::: "memory");
    else             asm volatile("s_waitcnt vmcnt(0)" ::: "memory");
    __builtin_amdgcn_s_barrier();
    asm volatile("" ::: "memory");
    const signed char* A = As[cb];
    const signed char* B = Bs[cb];

    // ---- phase 0: A frags m0..3, all B frags; stage A0/Bgate of kt+2 ----
    v4i af[4], bg0, bg1, bu0, bu1;
    #pragma unroll
    for (int m = 0; m < 4; ++m) af[m] = *(const v4i*)&A[abase + m * 256];
    bg0 = *(const v4i*)&B[gbase];
    bg1 = *(const v4i*)&B[gbase + 256];
    bu0 = *(const v4i*)&B[8192 + gbase];
    bu1 = *(const v4i*)&B[8192 + gbase + 256];
    if (kt + 2 < nk) stage01(kt + 2, sb);
    __builtin_amdgcn_s_barrier();
    asm volatile("s_waitcnt lgkmcnt(0)" ::: "memory");
    __builtin_amdgcn_sched_barrier(0);
    __builtin_amdgcn_s_setprio(1);
    #pragma unroll
    for (int m = 0; m < 4; ++m) {
      accg[m][0] = __builtin_amdgcn_mfma_i32_16x16x64_i8(af[m], bg0, accg[m][0], 0, 0, 0);
      accg[m][1] = __builtin_amdgcn_mfma_i32_16x16x64_i8(af[m], bg1, accg[m][1], 0, 0, 0);
      accu[m][0] = __builtin_amdgcn_mfma_i32_16x16x64_i8(af[m], bu0, accu[m][0], 0, 0, 0);
      accu[m][1] = __builtin_amdgcn_mfma_i32_16x16x64_i8(af[m], bu1, accu[m][1], 0, 0, 0);
    }
    __builtin_amdgcn_s_setprio(0);

    // ---- phase 1: A frags m4..7 (B held in regs); stage A1/Bup of kt+2 ----
    v4i af2[4];
    #pragma unroll
    for (int m = 0; m < 4; ++m) af2[m] = *(const v4i*)&A[abase + 1024 + m * 256];
    if (kt + 2 < nk) stage23(kt + 2, sb);
    __builtin_amdgcn_s_barrier();
    asm volatile("s_waitcnt lgkmcnt(0)" ::: "memory");
    __builtin_amdgcn_sched_barrier(0);
    __builtin_amdgcn_s_setprio(1);
    #pragma unroll
    for (int m = 0; m < 4; ++m) {
      accg[m + 4][0] = __builtin_amdgcn_mfma_i32_16x16x64_i8(af2[m], bg0, accg[m + 4][0], 0, 0, 0);
      accg[m + 4][1] = __builtin_amdgcn_mfma_i32_16x16x64_i8(af2[m], bg1, accg[m + 4][1], 0, 0, 0);
      accu[m + 4][0] = __builtin_amdgcn_mfma_i32_16x16x64_i8(af2[m], bu0, accu[m + 4][0], 0, 0, 0);
      accu[m + 4][1] = __builtin_amdgcn_mfma_i32_16x16x64_i8(af2[m], bu1, accu[m + 4][1], 0, 0, 0);
    }
    __builtin_amdgcn_s_setprio(0);

    cb = (cb + 1 == 3) ? 0 : cb + 1;
    sb = (sb + 1 == 3) ? 0 : sb + 1;
  }

  // epilogue: dequant + silu*mul, write h, track max|h|
  const float xsc = __uint_as_float(scal[0]) * (1.0f / QMAXF);
  float hmax = 0.f;
  #pragma unroll
  for (int m = 0; m < 8; ++m) {
    const int row0 = brow + wr * 128 + m * 16 + klg * 4;
    #pragma unroll
    for (int n = 0; n < 2; ++n) {
      const int col = bcol + wc * 32 + n * 16 + ln15;
      const float sg = sgu[col] * xsc;
      const float su = sgu[I_DIM + col] * xsc;
      #pragma unroll
      for (int q = 0; q < 4; ++q) {
        float g = (float)accg[m][n][q] * sg;
        float u = (float)accu[m][n][q] * su;
        float hv = (g / (1.f + expf(-g))) * u;
        hmax = fmaxf(hmax, fabsf(hv));
        hbuf[(size_t)(row0 + q) * I_DIM + col] = hv;
      }
    }
  }
  #pragma unroll
  for (int off = 32; off; off >>= 1) hmax = fmaxf(hmax, __shfl_xor(hmax, off));
  if (lane == 0) atomicMax(scal + 1, __float_as_uint(hmax));
}

// ---------------- quantize h ----------------

__global__ void quant_h_kernel(const float4* __restrict__ h4, v4i* __restrict__ q4,
                               const unsigned* __restrict__ scal) {
  const float hs = __uint_as_float(scal[1]) * (1.0f / QMAXF);
  const long i = (long)blockIdx.x * blockDim.x + threadIdx.x;
  v4i o;
  #pragma unroll
  for (int j = 0; j < 4; ++j) {
    float4 v = h4[i * 4 + j];
    float a = fminf(fmaxf(rintf(v.x / hs), -QMAXF), QMAXF);
    float b = fminf(fmaxf(rintf(v.y / hs), -QMAXF), QMAXF);
    float c = fminf(fmaxf(rintf(v.z / hs), -QMAXF), QMAXF);
    float d = fminf(fmaxf(rintf(v.w / hs), -QMAXF), QMAXF);
    o[j] = packq(a, b, c, d);
  }
  q4[i] = o;
}

__global__ void hscale_out_kernel(const unsigned* __restrict__ scal, float* __restrict__ dst) {
  dst[0] = __uint_as_float(scal[1]) * (1.0f / QMAXF);
}

// ---------------- GEMM2: out = (qh @ wdn^T) * (h_scale * s_down) ----------------
// BM=256 x BN=128, BK=64. 8 waves (4 row x 2 col), per-wave 64x64 out.
// Same 3-buffer distance-2 pipeline, 1 phase of 16 MFMA per K-tile.

__global__ __launch_bounds__(512, 4)
void gemm2_kernel(const signed char* __restrict__ qh,
                  const signed char* __restrict__ w8,
                  const float* __restrict__ sdn,
                  const unsigned* __restrict__ scal,
                  float* __restrict__ out)
{
  __shared__ signed char As[3][16384];
  __shared__ signed char Bs[3][8192];

  const int tid  = threadIdx.x;
  const int lane = tid & 63;
  const int wid  = tid >> 6;
  const int wr   = wid >> 1;       // 0..3 (64-row group)
  const int wc   = wid & 1;        // 0..1 (64-col group)
  const int ln15 = lane & 15;
  const int klg  = lane >> 4;

  const int lin = blockIdx.x;                  // 0..511 = 8*64
  const int sw  = (lin & 7) * 64 + (lin >> 3);
  const int brow = (sw & 15) * 256;
  const int bcol = (sw >> 4) * 128;

  const int sr = tid & 127, ss = tid >> 7;
  const signed char* gA0 = qh + (size_t)(brow + sr) * I_DIM + ss * 16;
  const signed char* gA1 = qh + (size_t)(brow + 128 + sr) * I_DIM + ss * 16;
  const signed char* gB  = w8 + (size_t)(bcol + sr) * I_DIM + ss * 16;
  const int l0 = tid * 16, l1 = 8192 + tid * 16;

  const int abase = (wr >> 1) * 8192 + klg * 2048 + ((wr & 1) * 64 + ln15) * 16;
  const int bbase = klg * 2048 + (wc * 64 + ln15) * 16;

  v4i zero = {0, 0, 0, 0};
  v4i acc[4][4];
  #pragma unroll
  for (int m = 0; m < 4; ++m)
    #pragma unroll
    for (int n = 0; n < 4; ++n) acc[m][n] = zero;

  auto stage = [&](int kt, int b) {
    gload16(gA0 + kt * 64, &As[b][l0]);
    gload16(gA1 + kt * 64, &As[b][l1]);
    gload16(gB  + kt * 64, &Bs[b][tid * 16]);
  };

  stage(0, 0);
  stage(1, 1);
  const int nk = I_DIM / 64;  // 172
  int cb = 0, sb = 2;
  for (int kt = 0; kt < nk; ++kt) {
    if (kt < nk - 1) asm volatile("s_waitcnt vmcnt(3)" ::: "memory");
    else             asm volatile("s_waitcnt vmcnt(0)" ::: "memory");
    __builtin_amdgcn_s_barrier();
    asm volatile("" ::: "memory");
    const signed char* A = As[cb];
    const signed char* B = Bs[cb];

    v4i af[4], bf[4];
    #pragma unroll
    for (int m = 0; m < 4; ++m) af[m] = *(const v4i*)&A[abase + m * 256];
    #pragma unroll
    for (int n = 0; n < 4; ++n) bf[n] = *(const v4i*)&B[bbase + n * 256];
    if (kt + 2 < nk) stage(kt + 2, sb);
    __builtin_amdgcn_s_barrier();
    asm volatile("s_waitcnt lgkmcnt(0)" ::: "memory");
    __builtin_amdgcn_sched_barrier(0);
    __builtin_amdgcn_s_setprio(1);
    #pragma unroll
    for (int m = 0; m < 4; ++m)
      #pragma unroll
      for (int n = 0; n < 4; ++n)
        acc[m][n] = __builtin_amdgcn_mfma_i32_16x16x64_i8(af[m], bf[n], acc[m][n], 0, 0, 0);
    __builtin_amdgcn_s_setprio(0);

    cb = (cb + 1 == 3) ? 0 : cb + 1;
    sb = (sb + 1 == 3) ? 0 : sb + 1;
  }

  const float hsc = __uint_as_float(scal[1]) * (1.0f / QMAXF);
  #pragma unroll
  for (int m = 0; m < 4; ++m) {
    const int row0 = brow + wr * 64 + m * 16 + klg * 4;
    #pragma unroll
    for (int n = 0; n < 4; ++n) {
      const int col = bcol + wc * 64 + n * 16 + ln15;
      const float s = sdn[col] * hsc;
      #pragma unroll
      for (int q = 0; q < 4; ++q)
        out[(size_t)(row0 + q) * K1 + col] = (float)acc[m][n][q] * s;
    }
  }
}

// ---------------- launch ----------------

extern "C" void kernel_launch(void* const* d_in, const int* in_sizes, int n_in,
                              void* d_out, int out_size, void* d_ws, size_t ws_size,
                              hipStream_t stream) {
  (void)in_sizes; (void)n_in; (void)out_size; (void)ws_size;
  const float* x   = (const float*)d_in[0];
  const float* wgu = (const float*)d_in[1];
  const float* sgu = (const float*)d_in[2];
  const float* wdn = (const float*)d_in[3];
  const float* sdn = (const float*)d_in[4];
  float* out = (float*)d_out;
  char* ws = (char*)d_ws;

  // ws layout (16B aligned): total ~360 MB
  signed char* qx  = (signed char*)(ws + 0LL);           // 16,777,216
  signed char* w8g = (signed char*)(ws + 16777216LL);    // 90,177,536
  signed char* w8d = (signed char*)(ws + 106954752LL);   // 45,088,768
  signed char* qh  = (signed char*)(ws + 152043520LL);   // 45,088,768
  float*       hb  = (float*)      (ws + 197132288LL);   // 180,355,072
  unsigned*    scal= (unsigned*)   (ws + 377487360LL);   // 256

  hipMemsetAsync(scal, 0, 256, stream);
  absmax_x_kernel<<<2048, 256, 0, stream>>>((const float4*)x, scal, T_DIM * K1 / 4);
  quant_x_kernel<<<4096, 256, 0, stream>>>((const float4*)x, (v4i*)qx, scal);
  conv_w_kernel<<<22016, 256, 0, stream>>>((const float4*)wgu, (v4i*)w8g);
  conv_w_kernel<<<11008, 256, 0, stream>>>((const float4*)wdn, (v4i*)w8d);

  gemm1_silu_kernel<<<1376, 512, 0, stream>>>(qx, w8g, sgu, scal, hb);

  quant_h_kernel<<<11008, 256, 0, stream>>>((const float4*)hb, (v4i*)qh, scal);
  hscale_out_kernel<<<1, 1, 0, stream>>>(scal, out + (size_t)T_DIM * K1);

  gemm2_kernel<<<512, 512, 0, stream>>>(qh, w8d, sdn, scal, out);
}